// Round 1
// 147.545 us; speedup vs baseline: 1.1283x; 1.1283x over previous
//
#include <hip/hip_runtime.h>

#define DDIM 256
#define HDIM 128
#define KLEN 1024
// 2*log2(e): exp2(SCL*x) == e^{2x}
#define SCL 2.8853900817779268f

// ============ Projection -> Eq/Ek = exp2(SCL * in@W) ============
// v2: wave-uniform W (scalar s_load path) x per-lane rows.
// Block = 64 rows x 32 h = 4 waves; each wave owns 8 h, each lane owns 1 row.
// A-tile (64 rows x 64 d) in LDS, XOR-swizzled on 16B granules so each
// lane's ds_read_b128 of its own row is <=2-way (free). W operands are
// wave-uniform -> scalar loads, costing no VALU/VMEM/LDS bandwidth:
// 0.5 B/fma of LDS traffic (64 B/clk/CU at full VALU rate, under ceilings).
// Grid 1088 (4.25 blocks/CU): 1024 key blocks (XCD-swizzled) + 64 query.
// Output layouts identical to v1 (Eq row-major, Ek [b][h][k], exp2 applied).
__global__ __launch_bounds__(256) void proj_kernel(
    const float* __restrict__ queries, const float* __restrict__ keys,
    const float* __restrict__ W_q, const float* __restrict__ W_k,
    float* __restrict__ Eq, float* __restrict__ Ek)
{
    __shared__ union {
        float a[64 * 64];    // 16 KB A-tile (swizzled)
        float t[32][68];     // epilogue transpose staging (keys), pad 64->68
    } sm;

    const int tid  = threadIdx.x;
    const int lane = tid & 63;
    const int wav  = tid >> 6;

    int blk = blockIdx.x;
    bool iskey; int b = 0, kc0 = 0, hb, row0;
    const float* in; const float* W;
    if (blk < 1024) {
        iskey = true;
        int xcd = blk & 7, s = blk >> 3;
        b = ((s >> 6) << 3) | xcd;
        int r6 = s & 63;
        kc0 = (r6 >> 2) << 6;     // 16 k-chunks of 64
        hb  = (r6 & 3) << 5;      // 4 h-chunks of 32
        row0 = b * KLEN + kc0;
        in = keys; W = W_k;
    } else {
        iskey = false;
        int qrb = blk - 1024;     // 0..63
        row0 = (qrb >> 2) << 6;
        hb   = (qrb & 3) << 5;
        in = queries; W = W_q;
    }

    // wave-uniform h-base -> W accesses become scalar loads
    const int hg8 = __builtin_amdgcn_readfirstlane(wav << 3);
    const float* Wu = W + hb + hg8;

    // staging: 4 x 16B granules per thread per 64-d step, coalesced reads
    const int srow = tid >> 4;        // 0..15 (+16*i covers 64 rows)
    const int sgd  = tid & 15;        // 16B granule within 64-d row slice
    const float* gsrc = in + (size_t)(row0 + srow) * DDIM + (sgd << 2);

    float4 pf0 = *(const float4*)(gsrc);
    float4 pf1 = *(const float4*)(gsrc + 16 * DDIM);
    float4 pf2 = *(const float4*)(gsrc + 32 * DDIM);
    float4 pf3 = *(const float4*)(gsrc + 48 * DDIM);

    float acc[8];
    #pragma unroll
    for (int c = 0; c < 8; c++) acc[c] = 0.f;

    // XOR-swizzled LDS write offsets (float index): granule ^= (row & 7)
    const int w0 = (srow)      * 64 + ((sgd ^ ((srow)      & 7)) << 2);
    const int w1 = (srow + 16) * 64 + ((sgd ^ ((srow + 16) & 7)) << 2);
    const int w2 = (srow + 32) * 64 + ((sgd ^ ((srow + 32) & 7)) << 2);
    const int w3 = (srow + 48) * 64 + ((sgd ^ ((srow + 48) & 7)) << 2);

    for (int dt0 = 0; dt0 < DDIM; dt0 += 64) {
        *(float4*)(sm.a + w0) = pf0;
        *(float4*)(sm.a + w1) = pf1;
        *(float4*)(sm.a + w2) = pf2;
        *(float4*)(sm.a + w3) = pf3;
        __syncthreads();
        if (dt0 < DDIM - 64) {        // prefetch next d-tile under compute
            const float* g2 = gsrc + dt0 + 64;
            pf0 = *(const float4*)(g2);
            pf1 = *(const float4*)(g2 + 16 * DDIM);
            pf2 = *(const float4*)(g2 + 32 * DDIM);
            pf3 = *(const float4*)(g2 + 48 * DDIM);
        }
        const float* arow = sm.a + lane * 64;
        const int lx = lane & 7;
        #pragma unroll
        for (int d4 = 0; d4 < 64; d4 += 4) {
            float4 a = *(const float4*)(arow + ((((d4 >> 2)) ^ lx) << 2));
            const float* wr = Wu + (size_t)(dt0 + d4) * HDIM;
            #pragma unroll
            for (int c = 0; c < 8; c++) acc[c] = fmaf(a.x, wr[c],            acc[c]);
            #pragma unroll
            for (int c = 0; c < 8; c++) acc[c] = fmaf(a.y, wr[HDIM + c],     acc[c]);
            #pragma unroll
            for (int c = 0; c < 8; c++) acc[c] = fmaf(a.z, wr[2 * HDIM + c], acc[c]);
            #pragma unroll
            for (int c = 0; c < 8; c++) acc[c] = fmaf(a.w, wr[3 * HDIM + c], acc[c]);
        }
        __syncthreads();   // compute done before next tile overwrites LDS
    }

    float e[8];
    #pragma unroll
    for (int c = 0; c < 8; c++) e[c] = __builtin_amdgcn_exp2f(SCL * acc[c]);

    if (!iskey) {
        float* dst = Eq + (size_t)(row0 + lane) * HDIM + hb + hg8;
        *(float4*)(dst)     = make_float4(e[0], e[1], e[2], e[3]);
        *(float4*)(dst + 4) = make_float4(e[4], e[5], e[6], e[7]);
    } else {
        // transpose 64k x 32h -> t[h][k], then coalesced 256B-row stores
        #pragma unroll
        for (int c = 0; c < 8; c++) sm.t[(wav << 3) + c][lane] = e[c];
        __syncthreads();
        float* dstb = Ek + (size_t)b * HDIM * KLEN + (size_t)hb * KLEN + kc0;
        #pragma unroll
        for (int i = 0; i < 2; i++) {
            int g = tid + (i << 8);
            int h = g >> 4, k4 = (g & 15) << 2;
            float4 o = *(const float4*)(&sm.t[h][k4]);
            *(float4*)(dstb + (size_t)h * KLEN + k4) = o;
        }
    }
}

// ============ Scores + masked softmax ============
// Grid 512 (XCD-swizzled), 512 threads (8 waves). Block = (b, q-pair).
// Thread owns 2 contiguous k. tanh via r = rcp(Eq*Ek + 1): 1 trans + 2 fma
// per element. (Eq0,Eq1,w2) broadcast from LDS as one float4 per h.
__global__ __launch_bounds__(512) void score_kernel(
    const float* __restrict__ Eq, const float* __restrict__ Ek,
    const float* __restrict__ w_v, const int* __restrict__ valid_lens,
    float* __restrict__ p)
{
    __shared__ float4 eqw[HDIM];
    __shared__ float red0[8], red1[8];

    int tid = threadIdx.x, lane = tid & 63, wav = tid >> 6;
    int blk = blockIdx.x;
    int xcd = blk & 7, s = blk >> 3;
    int b = ((s >= 32) ? 8 : 0) + xcd;
    int qp = s & 31;
    int bq0 = b * 64 + qp * 2;
    int vlen = valid_lens[b];

    if (tid < HDIM) {
        float w2 = -2.0f * w_v[tid];
        eqw[tid] = make_float4(Eq[(size_t)bq0 * HDIM + tid],
                               Eq[(size_t)(bq0 + 1) * HDIM + tid], w2, 0.f);
    }
    __syncthreads();

    int k0 = tid << 1;
    float s00 = -1e30f, s01 = -1e30f, s10 = -1e30f, s11 = -1e30f;
    if (k0 < vlen) {
        const float* ekp = Ek + (size_t)b * HDIM * KLEN + k0;
        float a00 = 0.f, a01 = 0.f, a10 = 0.f, a11 = 0.f;
        #pragma unroll 4
        for (int h = 0; h < HDIM; h++) {
            float2 ek = *(const float2*)(ekp + (size_t)h * KLEN);
            float4 e  = eqw[h];
            a00 = fmaf(e.z, __builtin_amdgcn_rcpf(fmaf(e.x, ek.x, 1.f)), a00);
            a01 = fmaf(e.z, __builtin_amdgcn_rcpf(fmaf(e.x, ek.y, 1.f)), a01);
            a10 = fmaf(e.z, __builtin_amdgcn_rcpf(fmaf(e.y, ek.x, 1.f)), a10);
            a11 = fmaf(e.z, __builtin_amdgcn_rcpf(fmaf(e.y, ek.y, 1.f)), a11);
        }
        s00 = a00; s10 = a10;
        if (k0 + 1 < vlen) { s01 = a01; s11 = a11; }
    }

    float m0 = fmaxf(s00, s01), m1 = fmaxf(s10, s11);
    #pragma unroll
    for (int off = 32; off > 0; off >>= 1) {
        m0 = fmaxf(m0, __shfl_xor(m0, off, 64));
        m1 = fmaxf(m1, __shfl_xor(m1, off, 64));
    }
    if (lane == 0) { red0[wav] = m0; red1[wav] = m1; }
    __syncthreads();
    m0 = red0[0]; m1 = red1[0];
    #pragma unroll
    for (int i = 1; i < 8; i++) {
        m0 = fmaxf(m0, red0[i]);
        m1 = fmaxf(m1, red1[i]);
    }

    float e00 = __expf(s00 - m0), e01 = __expf(s01 - m0);   // masked -> exact 0
    float e10 = __expf(s10 - m1), e11 = __expf(s11 - m1);
    float t0 = e00 + e01, t1 = e10 + e11;
    #pragma unroll
    for (int off = 32; off > 0; off >>= 1) {
        t0 += __shfl_xor(t0, off, 64);
        t1 += __shfl_xor(t1, off, 64);
    }
    __syncthreads();
    if (lane == 0) { red0[wav] = t0; red1[wav] = t1; }
    __syncthreads();
    t0 = red0[0]; t1 = red1[0];
    #pragma unroll
    for (int i = 1; i < 8; i++) { t0 += red0[i]; t1 += red1[i]; }
    float inv0 = 1.0f / t0, inv1 = 1.0f / t1;

    float* p0 = p + (size_t)bq0 * KLEN + k0;
    *(float2*)(p0)        = make_float2(e00 * inv0, e01 * inv0);
    *(float2*)(p0 + KLEN) = make_float2(e10 * inv1, e11 * inv1);
}

// ============ attn @ V ============
// Grid 1024 = (16 b) x (8 q-tiles of 8) x (8 k-eighths of 128), XCD-swizzled.
// p-tile transposed into LDS once; inner loop = ds b64 broadcast + coalesced
// float4 V + 8 fma. Wave owns 2 q, lanes own d4. Always stores -> poison-safe.
__global__ __launch_bounds__(256) void av_kernel(
    const float* __restrict__ p, const float* __restrict__ values,
    const int* __restrict__ valid_lens, float* __restrict__ part)
{
    __shared__ float pt[128][10];   // [k][q], pad 8->10 keeps b64 alignment

    int blk = blockIdx.x;
    int xcd = blk & 7, s = blk >> 3;
    int b = ((s >> 6) << 3) | xcd;
    int r = s & 63, qt = r >> 3, kq = r & 7;
    int tid = threadIdx.x, lane = tid & 63, w = tid >> 6;
    int vlen = valid_lens[b];
    int kbeg = kq << 7;
    int kc = vlen - kbeg; kc = kc < 0 ? 0 : (kc > 128 ? 128 : kc);
    int kc4 = (kc + 3) & ~3;        // p is exactly 0 beyond vlen -> safe round-up
    int bq0 = b * 64 + qt * 8;

    {   // stage p[8q][128k] -> pt[k][q]
        int q = tid >> 5, k4 = (tid & 31) << 2;
        float4 pv = *(const float4*)(p + (size_t)(bq0 + q) * KLEN + kbeg + k4);
        pt[k4 + 0][q] = pv.x;
        pt[k4 + 1][q] = pv.y;
        pt[k4 + 2][q] = pv.z;
        pt[k4 + 3][q] = pv.w;
    }
    __syncthreads();

    const float* vb = values + ((size_t)b * KLEN + kbeg) * DDIM + (lane << 2);
    float4 a0 = make_float4(0.f, 0.f, 0.f, 0.f);
    float4 a1 = make_float4(0.f, 0.f, 0.f, 0.f);

    for (int k = 0; k < kc4; k += 4) {
        #pragma unroll
        for (int i = 0; i < 4; i++) {
            float2 pp = *(const float2*)(&pt[k + i][w << 1]);
            float4 v  = *(const float4*)(vb + (size_t)(k + i) * DDIM);
            a0.x = fmaf(pp.x, v.x, a0.x); a0.y = fmaf(pp.x, v.y, a0.y);
            a0.z = fmaf(pp.x, v.z, a0.z); a0.w = fmaf(pp.x, v.w, a0.w);
            a1.x = fmaf(pp.y, v.x, a1.x); a1.y = fmaf(pp.y, v.y, a1.y);
            a1.z = fmaf(pp.y, v.z, a1.z); a1.w = fmaf(pp.y, v.w, a1.w);
        }
    }
    float* d0 = part + ((size_t)kq * 1024 + bq0 + (w << 1)) * DDIM + (lane << 2);
    *(float4*)(d0)        = a0;
    *(float4*)(d0 + DDIM) = a1;
}

// ============ sum 8 k-partials ============
__global__ __launch_bounds__(256) void combine_kernel(
    const float* __restrict__ part, float* __restrict__ out)
{
    int i = blockIdx.x * 256 + threadIdx.x;        // 65536 float4 slots
    const float4* p4 = (const float4*)part;
    float4 a = p4[i];
    #pragma unroll
    for (int j = 1; j < 8; j++) {
        float4 v = p4[(size_t)j * 65536 + i];
        a.x += v.x; a.y += v.y; a.z += v.z; a.w += v.w;
    }
    ((float4*)out)[i] = a;
}

extern "C" void kernel_launch(void* const* d_in, const int* in_sizes, int n_in,
                              void* d_out, int out_size, void* d_ws, size_t ws_size,
                              hipStream_t stream) {
    const float* queries    = (const float*)d_in[0]; // [16,64,256]
    const float* keys       = (const float*)d_in[1]; // [16,1024,256]
    const float* values     = (const float*)d_in[2]; // [16,1024,256]
    const int*   valid_lens = (const int*)d_in[3];   // [16]
    const float* W_q        = (const float*)d_in[4]; // [256,128]
    const float* W_k        = (const float*)d_in[5]; // [256,128]
    const float* w_v        = (const float*)d_in[6]; // [128]

    float* Eq   = (float*)d_ws;            // 1024*128     = 512 KB
    float* Ek   = Eq + 131072;             // 16*128*1024  = 8 MB
    float* p    = Ek + 2097152;            // 1024*1024    = 4 MB
    float* part = Ek;                      // alias: Ek dead after score; 8 MB exact

    proj_kernel<<<1088, 256, 0, stream>>>(queries, keys, W_q, W_k, Eq, Ek);
    score_kernel<<<512, 512, 0, stream>>>(Eq, Ek, w_v, valid_lens, p);
    av_kernel<<<1024, 256, 0, stream>>>(p, values, valid_lens, part);
    combine_kernel<<<256, 256, 0, stream>>>(part, (float*)d_out);
}